// Round 5
// baseline (447.132 us; speedup 1.0000x reference)
//
#include <hip/hip_runtime.h>
#include <hip/hip_bf16.h>
#include <math.h>

#define B_  4
#define S_  2048
#define D_  1024
#define H_  16
#define DK_ 64
#define M_  (B_ * S_)   // 8192 rows

typedef short short8 __attribute__((ext_vector_type(8)));
typedef float floatx4 __attribute__((ext_vector_type(4)));

__device__ inline unsigned short f2bf(float x) {
    unsigned u = __float_as_uint(x);
    u = (u + 0x7fff + ((u >> 16) & 1)) >> 16;   // round-to-nearest-even
    return (unsigned short)u;
}
__device__ inline float bf2f(unsigned short h) {
    return __uint_as_float(((unsigned)h) << 16);
}

// packed f32x2 -> bf16x2 (RNE), single VALU op
__device__ inline unsigned cvt_pk_bf16(float lo, float hi) {
    unsigned r;
    asm("v_cvt_pk_bf16_f32 %0, %1, %2" : "=v"(r) : "v"(lo), "v"(hi));
    return r;
}

// DPP row rotate (within 16-lane row) — VALU-pipe cross-lane
template <int K>
__device__ inline float dpp_ror(float x) {
    return __uint_as_float((unsigned)__builtin_amdgcn_update_dpp(
        0, (int)__float_as_uint(x), 0x120 | K, 0xF, 0xF, true));
}
__device__ inline float rowmax16(float x) {
    x = fmaxf(x, dpp_ror<8>(x));
    x = fmaxf(x, dpp_ror<4>(x));
    x = fmaxf(x, dpp_ror<2>(x));
    x = fmaxf(x, dpp_ror<1>(x));
    return x;
}
__device__ inline float rowsum16(float x) {
    x += dpp_ror<8>(x);
    x += dpp_ror<4>(x);
    x += dpp_ror<2>(x);
    x += dpp_ror<1>(x);
    return x;
}

#define GLOAD_LDS16(g, l)                                          \
    __builtin_amdgcn_global_load_lds(                              \
        (const __attribute__((address_space(1))) void*)(g),        \
        (__attribute__((address_space(3))) void*)(l), 16, 0, 0)

// ---------------------------------------------------------------------------
// fp32 -> bf16 converters
// ---------------------------------------------------------------------------
__global__ __launch_bounds__(256) void cvt_inputs_kernel(
    const float* __restrict__ q, const float* __restrict__ k,
    const float* __restrict__ v, unsigned short* __restrict__ Ah)
{
    const int z = blockIdx.z;
    const float* src = (z == 0) ? q : (z == 1) ? k : v;
    unsigned short* dst = Ah + (size_t)z * M_ * D_;
    const size_t i = ((size_t)blockIdx.x * 256 + threadIdx.x) * 4;
    float4 f = *(const float4*)(src + i);
    ushort4 o;
    o.x = f2bf(f.x); o.y = f2bf(f.y); o.z = f2bf(f.z); o.w = f2bf(f.w);
    *(ushort4*)(dst + i) = o;
}

__global__ __launch_bounds__(256) void cvt_weights_kernel(
    const float* __restrict__ wq, const float* __restrict__ wk,
    const float* __restrict__ wv, const float* __restrict__ wo,
    unsigned short* __restrict__ Wh, unsigned short* __restrict__ Woh)
{
    const int z = blockIdx.z;
    const float* src = (z == 0) ? wq : (z == 1) ? wk : (z == 2) ? wv : wo;
    unsigned short* dst = (z < 3) ? (Wh + (size_t)z * D_ * D_) : Woh;
    const size_t i = ((size_t)blockIdx.x * 256 + threadIdx.x) * 4;
    float4 f = *(const float4*)(src + i);
    ushort4 o;
    o.x = f2bf(f.x); o.y = f2bf(f.y); o.z = f2bf(f.z); o.w = f2bf(f.w);
    *(ushort4*)(dst + i) = o;
}

// ---------------------------------------------------------------------------
// bf16 MFMA NT-GEMM: C = A @ W^T + bias.  T3 "minimum 2-phase": double-
// buffered LDS, stage tile k+1 via async global_load_lds DURING compute of
// tile k, ONE barrier per k-step (the implicit vmcnt-drain at the barrier
// lands after ~16 MFMAs of cover instead of immediately after issue).
// MODE 0: fp32 row-major out (O-proj).
// MODE 1: bf16; z=0/1 (Q/K) -> [B,H,S,DK]; z=2 (V) -> [B,H,DK,S]. Both
//         epilogues repack through per-wave LDS (aliasing As, post-barrier)
//         so all global stores are 16B coalesced. NOTE: each lane must
//         read/store TWO short8 (quad*16 and quad*16+8) to cover the full
//         16x64 strip — round-4 bug was storing only the first half.
// ---------------------------------------------------------------------------
template <int MODE>
__global__ __launch_bounds__(256) void gemm_bf16_kernel(
    const unsigned short* __restrict__ Ah, const unsigned short* __restrict__ Wh,
    const float* __restrict__ bq, const float* __restrict__ bk,
    const float* __restrict__ bv, void* __restrict__ outv)
{
    __shared__ __align__(16) unsigned short As[2][128 * 32];   // [buf][m][k]
    __shared__ __align__(16) unsigned short Bs[2][128 * 32];   // [buf][n][k]

    const int tid  = threadIdx.x;
    const int wave = tid >> 6;
    const int lane = tid & 63;
    const int quad = lane >> 4;
    const int l15  = lane & 15;
    const int z    = (MODE == 1) ? blockIdx.z : 0;
    const int m0   = blockIdx.x * 128;
    const int n0   = blockIdx.y * 128;
    const int wrow = (wave >> 1) * 64;
    const int wcol = (wave & 1) * 64;

    const unsigned short* A = Ah + (size_t)z * M_ * D_;
    const unsigned short* W = Wh + (size_t)z * D_ * D_;

    const int srow   = tid >> 2;          // 0..63
    const int schunk = (tid & 3) * 8;

#define STAGE_G(BUF, K0)                                                     \
    {                                                                        \
        GLOAD_LDS16(A + (size_t)(m0 + srow) * D_ + (K0) + schunk,            \
                    &As[BUF][wave * 512]);                                   \
        GLOAD_LDS16(W + (size_t)(n0 + srow) * D_ + (K0) + schunk,            \
                    &Bs[BUF][wave * 512]);                                   \
        GLOAD_LDS16(A + (size_t)(m0 + 64 + srow) * D_ + (K0) + schunk,       \
                    &As[BUF][2048 + wave * 512]);                            \
        GLOAD_LDS16(W + (size_t)(n0 + 64 + srow) * D_ + (K0) + schunk,       \
                    &Bs[BUF][2048 + wave * 512]);                            \
    }

    floatx4 acc[4][4] = {};

    STAGE_G(0, 0);
    __syncthreads();

    for (int k0 = 0; k0 < D_; k0 += 32) {
        const int cur = (k0 >> 5) & 1;
        if (k0 + 32 < D_) STAGE_G(cur ^ 1, k0 + 32);

        short8 af[4], bf[4];
#pragma unroll
        for (int i = 0; i < 4; ++i)
            af[i] = *(const short8*)&As[cur][(wrow + i * 16 + l15) * 32 + quad * 8];
#pragma unroll
        for (int j = 0; j < 4; ++j)
            bf[j] = *(const short8*)&Bs[cur][(wcol + j * 16 + l15) * 32 + quad * 8];
#pragma unroll
        for (int i = 0; i < 4; ++i)
#pragma unroll
            for (int j = 0; j < 4; ++j)
                acc[i][j] = __builtin_amdgcn_mfma_f32_16x16x32_bf16(
                    af[i], bf[j], acc[i][j], 0, 0, 0);

        __syncthreads();   // drains staged DMA (after full MFMA cover) + LDS
    }
#undef STAGE_G

    const float* bias = (MODE == 0) ? bq : (z == 0) ? bq : (z == 1) ? bk : bv;

    if (MODE == 1) {
        // LDS repack epilogues; As free after final barrier. 16x68 strip/wave.
        unsigned short* Tw = (unsigned short*)As + wave * 16 * 68;
        const int bg = m0 >> 11;

        if (z == 2) {
            // V^T: [B,H,DK,S]; strip rows = n (dk), cols = m (s)
            const int s0g = (m0 & (S_ - 1)) + wrow + quad * 16;
#pragma unroll
            for (int j = 0; j < 4; ++j) {
                const int n = n0 + wcol + j * 16 + l15;
                const float bn = bias[n];
#pragma unroll
                for (int i = 0; i < 4; ++i)
#pragma unroll
                    for (int reg = 0; reg < 4; ++reg)
                        Tw[l15 * 68 + i * 16 + quad * 4 + reg] =
                            f2bf(acc[i][j][reg] + bn);
                // wave-local LDS: same-wave DS ops are in-order
                short8 r0 = *(const short8*)&Tw[l15 * 68 + quad * 16];
                short8 r1 = *(const short8*)&Tw[l15 * 68 + quad * 16 + 8];
                const int h = n >> 6, d = n & 63;
                unsigned short* dp = (unsigned short*)outv + 2 * (size_t)M_ * D_ +
                    (((size_t)(bg * H_ + h)) * DK_ + d) * S_ + s0g;
                *(short8*)(dp) = r0;
                *(short8*)(dp + 8) = r1;
            }
        } else {
            // Q/K: [B,H,S,DK]; strip rows = m (s), cols = n (dk). Wave's
            // n-range [n0+wcol, +64) is exactly one head -> rows contiguous.
            const int hq = (n0 + wcol) >> 6;
            const int sb = (m0 & (S_ - 1)) + wrow;
            unsigned short* dstz = (unsigned short*)outv + (size_t)z * M_ * D_;
#pragma unroll
            for (int i = 0; i < 4; ++i) {
#pragma unroll
                for (int j = 0; j < 4; ++j) {
                    const float bn = bias[n0 + wcol + j * 16 + l15];
#pragma unroll
                    for (int reg = 0; reg < 4; ++reg)
                        Tw[(quad * 4 + reg) * 68 + j * 16 + l15] =
                            f2bf(acc[i][j][reg] + bn);
                }
                short8 r0 = *(const short8*)&Tw[l15 * 68 + quad * 16];
                short8 r1 = *(const short8*)&Tw[l15 * 68 + quad * 16 + 8];
                unsigned short* dp = dstz +
                    (((size_t)bg * H_ + hq) * S_ + sb + i * 16 + l15) * DK_ +
                    quad * 16;
                *(short8*)dp = r0;
                *(short8*)(dp + 8) = r1;
            }
        }
        return;
    }

    // MODE 0: fp32 row-major (64B-contiguous per store instr)
#pragma unroll
    for (int j = 0; j < 4; ++j) {
        const int n = n0 + wcol + j * 16 + l15;
        const float bn = bias[n];
#pragma unroll
        for (int i = 0; i < 4; ++i) {
#pragma unroll
            for (int reg = 0; reg < 4; ++reg) {
                const int m = m0 + wrow + i * 16 + quad * 4 + reg;
                ((float*)outv)[(size_t)m * D_ + n] = acc[i][j][reg] + bn;
            }
        }
    }
}

// ---------------------------------------------------------------------------
// RoPE in-place on bf16 Q and K ([B*H, S, DK] compact). One wave per row.
// ---------------------------------------------------------------------------
__global__ __launch_bounds__(256) void rope_kernel(unsigned short* __restrict__ Q,
                                                   unsigned short* __restrict__ K)
{
    const int wave = blockIdx.x * 4 + (threadIdx.x >> 6);
    const int lane = threadIdx.x & 63;
    const int rowsPer = B_ * H_ * S_;

    unsigned short* base = (wave < rowsPer) ? Q : K;
    const int row = (wave < rowsPer) ? wave : wave - rowsPer;
    const int s = row & (S_ - 1);

    unsigned short* p = base + (size_t)row * DK_;
    const float v = bf2f(p[lane]);

    const int j = lane & 31;
    const float inv_freq = 1.0f / powf(10000.0f, (float)(2 * j) / (float)DK_);
    const float ang = (float)s * inv_freq;
    const float c  = cosf(ang);
    const float si = sinf(ang);

    const int partner = (lane < 32) ? (2 * lane + 1) : (2 * (lane - 32));
    const float sign = (lane < 32) ? -1.0f : 1.0f;
    const float pv = __shfl(v, partner);

    p[lane] = f2bf(v * c + sign * pv * si);
}

// ---------------------------------------------------------------------------
// MFMA flash attention, LDS-staged K/V via async global_load_lds (T3 2-phase).
// Grid 2048: one 64-row q-tile per block. L: xcd=L&7, bh=((L>>3)&7)*8+xcd,
// qt=31-(L>>6) (longest-first). All q-blocks of a head share an XCD.
// Defer-max (T13, THR=8 exp2-domain): keep the stale running max unless a
// row grew >8; skips alpha-exp2/rescale on most tiles. P <= 2^8, fp32
// l_i/acc absorb the headroom; rescale is exact when taken.
// ---------------------------------------------------------------------------
#define KSTR 72

__global__ __launch_bounds__(256, 3) void attn_kernel(
    const unsigned short* __restrict__ Qh, const unsigned short* __restrict__ Kh,
    const unsigned short* __restrict__ Vt, unsigned short* __restrict__ ctx)
{
    __shared__ __align__(16) unsigned short Ks[2][64 * 64];   // [s][dk] swz
    __shared__ __align__(16) unsigned short Vs[2][64 * 64];   // [dk][s] swz
    __shared__ __align__(16) short Pw[4][16 * KSTR];          // per-wave P strip

    const int tid  = threadIdx.x;
    const int wave = tid >> 6;
    const int lane = tid & 63;
    const int quad = lane >> 4;
    const int l15  = lane & 15;

    const int L  = blockIdx.x;
    const int bh = ((L >> 3) & 7) * 8 + (L & 7);
    const int qt = 31 - (L >> 6);        // longest-first dispatch
    const int q0 = qt * 64;

    const float c2 = 0.18033688011f;   // 0.125 * log2(e)

    const unsigned short* Kbase = Kh + (size_t)bh * S_ * DK_;
    const unsigned short* Vbase = Vt + (size_t)bh * DK_ * S_;
    const int b = bh >> 4, h = bh & 15;

    short* Pme = &Pw[wave][0];

    const unsigned short* Qrow =
        Qh + ((size_t)bh * S_ + q0 + wave * 16 + l15) * DK_;
    short8 aQ[2];
    aQ[0] = *(const short8*)(Qrow + quad * 8);
    aQ[1] = *(const short8*)(Qrow + 32 + quad * 8);

    // staging lane map: wave stages 8 rows x 8 granules (16B) per round;
    // source granule pre-swizzled so LDS (row, g) holds global (row, g^(row&7))
    const int srow = lane >> 3;              // 0..7: row within wave's strip
    const int sg   = (lane & 7) ^ srow;      // swizzled source granule
    const unsigned short* kSrc = Kbase + (size_t)(wave * 8 + srow) * DK_ + sg * 8;
    const unsigned short* vSrc = Vbase + (size_t)(wave * 8 + srow) * S_ + sg * 8;

    floatx4 acc[4] = {};
    float m_i[4] = {-INFINITY, -INFINITY, -INFINITY, -INFINITY};
    float l_i[4] = {0.f, 0.f, 0.f, 0.f};

    // prologue: stage tile j0=0 into buffer 0 (K rows: +rd*32 rows; V: same)
#pragma unroll
    for (int rd = 0; rd < 2; ++rd) {
        GLOAD_LDS16(kSrc + (size_t)rd * 32 * DK_, &Ks[0][rd * 2048 + wave * 512]);
        GLOAD_LDS16(vSrc + (size_t)rd * 32 * S_,  &Vs[0][rd * 2048 + wave * 512]);
    }
    __syncthreads();

    int buf = 0;
    for (int j0 = 0; j0 <= q0; j0 += 64) {
        // async stage of NEXT tile into the other buffer (overlaps compute)
        if (j0 + 64 <= q0) {
#pragma unroll
            for (int rd = 0; rd < 2; ++rd) {
                GLOAD_LDS16(kSrc + (size_t)(j0 + 64 + rd * 32) * DK_,
                            &Ks[buf ^ 1][rd * 2048 + wave * 512]);
                GLOAD_LDS16(vSrc + (j0 + 64) + (size_t)rd * 32 * S_,
                            &Vs[buf ^ 1][rd * 2048 + wave * 512]);
            }
        }

        // QK^T from LDS K tile (swizzled ds_read_b128)
        floatx4 st[4] = {};
#pragma unroll
        for (int t = 0; t < 4; ++t)
#pragma unroll
            for (int kh = 0; kh < 2; ++kh) {
                short8 kf = *(const short8*)&Ks[buf][(t * 16 + l15) * 64 +
                              ((((kh << 2) + quad) ^ (l15 & 7)) << 3)];
                st[t] = __builtin_amdgcn_mfma_f32_16x16x32_bf16(
                    aQ[kh], kf, st[t], 0, 0, 0);
            }

        // causal mask (diag tile only; wave-uniform branch)
        if (j0 == q0) {
#pragma unroll
            for (int t = 0; t < 4; ++t)
#pragma unroll
                for (int reg = 0; reg < 4; ++reg)
                    if (t * 16 + l15 > wave * 16 + quad * 4 + reg)
                        st[t][reg] = -INFINITY;
        }

        // online softmax, exp2 domain; defer-max; packed bf16 P-store
#pragma unroll
        for (int reg = 0; reg < 4; ++reg) {
            float rmx = fmaxf(fmaxf(st[0][reg], st[1][reg]),
                              fmaxf(st[2][reg], st[3][reg]));
            rmx = rowmax16(rmx);
            const float pm = rmx * c2;
            if (__ballot(pm > m_i[reg] + 8.0f) != 0ull) {
                const float m2 = fmaxf(m_i[reg], pm);
                const float alpha = exp2f(m_i[reg] - m2);
                l_i[reg] *= alpha;
                m_i[reg] = m2;
                if (__ballot(alpha == 1.0f) != ~0ull) {
#pragma unroll
                    for (int t = 0; t < 4; ++t) acc[t][reg] *= alpha;
                }
            }
            const float m2v = m_i[reg];

            const float p0 = exp2f(fmaf(st[0][reg], c2, -m2v));
            const float p1 = exp2f(fmaf(st[1][reg], c2, -m2v));
            const float p2 = exp2f(fmaf(st[2][reg], c2, -m2v));
            const float p3 = exp2f(fmaf(st[3][reg], c2, -m2v));

            const unsigned pk01 = cvt_pk_bf16(p0, p1);
            const unsigned pk23 = cvt_pk_bf16(p2, p3);
            const int rbase = (quad * 4 + reg) * KSTR + l15;
            Pme[rbase]      = (short)(unsigned short)pk01;
            Pme[rbase + 16] = (short)(unsigned short)(pk01 >> 16);
            Pme[rbase + 32] = (short)(unsigned short)pk23;
            Pme[rbase + 48] = (short)(unsigned short)(pk23 >> 16);

            float rs = (p0 + p1) + (p2 + p3);
            rs = rowsum16(rs);
            l_i[reg] += rs;
        }

        // PV: P A-frags from per-wave LDS, V B-frags from LDS tile (swizzled)
#pragma unroll
        for (int kh = 0; kh < 2; ++kh) {
            short8 aP = *(const short8*)&Pme[l15 * KSTR + kh * 32 + quad * 8];
#pragma unroll
            for (int t = 0; t < 4; ++t) {
                short8 vf = *(const short8*)&Vs[buf][(t * 16 + l15) * 64 +
                              ((((kh << 2) + quad) ^ (l15 & 7)) << 3)];
                acc[t] = __builtin_amdgcn_mfma_f32_16x16x32_bf16(
                    aP, vf, acc[t], 0, 0, 0);
            }
        }

        // flip buffers; __syncthreads drains vmcnt (staged DMA) + lgkmcnt
        __syncthreads();
        buf ^= 1;
    }

    // epilogue
#pragma unroll
    for (int reg = 0; reg < 4; ++reg) {
        const float inv = 1.0f / l_i[reg];
        const int q = q0 + wave * 16 + quad * 4 + reg;
        unsigned short* orow = ctx + ((size_t)b * S_ + q) * D_ + h * DK_;
#pragma unroll
        for (int t = 0; t < 4; ++t)
            orow[t * 16 + l15] = f2bf(acc[t][reg] * inv);
    }
}

// ---------------------------------------------------------------------------
extern "C" void kernel_launch(void* const* d_in, const int* in_sizes, int n_in,
                              void* d_out, int out_size, void* d_ws, size_t ws_size,
                              hipStream_t stream)
{
    const float* query = (const float*)d_in[0];
    const float* key   = (const float*)d_in[1];
    const float* value = (const float*)d_in[2];
    const float* w_q = (const float*)d_in[4];
    const float* b_q = (const float*)d_in[5];
    const float* w_k = (const float*)d_in[6];
    const float* b_k = (const float*)d_in[7];
    const float* w_v = (const float*)d_in[8];
    const float* b_v = (const float*)d_in[9];
    const float* w_o = (const float*)d_in[10];
    const float* b_o = (const float*)d_in[11];
    float* out = (float*)d_out;

    char* ws = (char*)d_ws;
    const size_t half = (size_t)M_ * D_ * sizeof(unsigned short);   // 16.78 MB
    unsigned short* Ah   = (unsigned short*)(ws);                    // [3][M,D] bf16
    unsigned short* Wh   = (unsigned short*)(ws + 3 * half);         // [3][D,D]
    unsigned short* Woh  = (unsigned short*)(ws + 3 * half + 3 * half / 8);
    unsigned short* QKVb = (unsigned short*)(ws + 3 * half + 4 * half / 8);
    unsigned short* Ctxh = (unsigned short*)(ws + 6 * half + 4 * half / 8);

    cvt_inputs_kernel<<<dim3(M_ * D_ / 1024, 1, 3), 256, 0, stream>>>(
        query, key, value, Ah);
    cvt_weights_kernel<<<dim3(D_ * D_ / 1024, 1, 4), 256, 0, stream>>>(
        w_q, w_k, w_v, w_o, Wh, Woh);

    gemm_bf16_kernel<1><<<dim3(M_ / 128, D_ / 128, 3), 256, 0, stream>>>(
        Ah, Wh, b_q, b_k, b_v, QKVb);

    unsigned short* Qb = QKVb;
    unsigned short* Kb = QKVb + (size_t)M_ * D_;
    unsigned short* Vb = QKVb + 2 * (size_t)M_ * D_;   // transposed [B,H,DK,S]

    rope_kernel<<<(2 * B_ * H_ * S_) / 4, 256, 0, stream>>>(Qb, Kb);

    attn_kernel<<<dim3(2048), 256, 0, stream>>>(Qb, Kb, Vb, Ctxh);

    gemm_bf16_kernel<0><<<dim3(M_ / 128, D_ / 128, 1), 256, 0, stream>>>(
        Ctxh, Woh, b_o, b_o, b_o, out);
}

// Round 6
// 393.782 us; speedup vs baseline: 1.1355x; 1.1355x over previous
//
#include <hip/hip_runtime.h>
#include <hip/hip_bf16.h>
#include <math.h>

#define B_  4
#define S_  2048
#define D_  1024
#define H_  16
#define DK_ 64
#define M_  (B_ * S_)   // 8192 rows

typedef short short8 __attribute__((ext_vector_type(8)));
typedef float floatx4 __attribute__((ext_vector_type(4)));

__device__ inline unsigned short f2bf(float x) {
    unsigned u = __float_as_uint(x);
    u = (u + 0x7fff + ((u >> 16) & 1)) >> 16;   // round-to-nearest-even
    return (unsigned short)u;
}
__device__ inline float bf2f(unsigned short h) {
    return __uint_as_float(((unsigned)h) << 16);
}

// packed f32x2 -> bf16x2 (RNE), single VALU op
__device__ inline unsigned cvt_pk_bf16(float lo, float hi) {
    unsigned r;
    asm("v_cvt_pk_bf16_f32 %0, %1, %2" : "=v"(r) : "v"(lo), "v"(hi));
    return r;
}

// DPP row rotate (within 16-lane row) — VALU-pipe cross-lane
template <int K>
__device__ inline float dpp_ror(float x) {
    return __uint_as_float((unsigned)__builtin_amdgcn_update_dpp(
        0, (int)__float_as_uint(x), 0x120 | K, 0xF, 0xF, true));
}
__device__ inline float rowmax16(float x) {
    x = fmaxf(x, dpp_ror<8>(x));
    x = fmaxf(x, dpp_ror<4>(x));
    x = fmaxf(x, dpp_ror<2>(x));
    x = fmaxf(x, dpp_ror<1>(x));
    return x;
}
__device__ inline float rowsum16(float x) {
    x += dpp_ror<8>(x);
    x += dpp_ror<4>(x);
    x += dpp_ror<2>(x);
    x += dpp_ror<1>(x);
    return x;
}

#define GLOAD_LDS16(g, l)                                          \
    __builtin_amdgcn_global_load_lds(                              \
        (const __attribute__((address_space(1))) void*)(g),        \
        (__attribute__((address_space(3))) void*)(l), 16, 0, 0)

// ---------------------------------------------------------------------------
// fp32 -> bf16 converters
// ---------------------------------------------------------------------------
__global__ __launch_bounds__(256) void cvt_inputs_kernel(
    const float* __restrict__ q, const float* __restrict__ k,
    const float* __restrict__ v, unsigned short* __restrict__ Ah)
{
    const int z = blockIdx.z;
    const float* src = (z == 0) ? q : (z == 1) ? k : v;
    unsigned short* dst = Ah + (size_t)z * M_ * D_;
    const size_t i = ((size_t)blockIdx.x * 256 + threadIdx.x) * 4;
    float4 f = *(const float4*)(src + i);
    ushort4 o;
    o.x = f2bf(f.x); o.y = f2bf(f.y); o.z = f2bf(f.z); o.w = f2bf(f.w);
    *(ushort4*)(dst + i) = o;
}

__global__ __launch_bounds__(256) void cvt_weights_kernel(
    const float* __restrict__ wq, const float* __restrict__ wk,
    const float* __restrict__ wv, const float* __restrict__ wo,
    unsigned short* __restrict__ Wh, unsigned short* __restrict__ Woh)
{
    const int z = blockIdx.z;
    const float* src = (z == 0) ? wq : (z == 1) ? wk : (z == 2) ? wv : wo;
    unsigned short* dst = (z < 3) ? (Wh + (size_t)z * D_ * D_) : Woh;
    const size_t i = ((size_t)blockIdx.x * 256 + threadIdx.x) * 4;
    float4 f = *(const float4*)(src + i);
    ushort4 o;
    o.x = f2bf(f.x); o.y = f2bf(f.y); o.z = f2bf(f.z); o.w = f2bf(f.w);
    *(ushort4*)(dst + i) = o;
}

// ---------------------------------------------------------------------------
// bf16 MFMA NT-GEMM: C = A @ W^T + bias.  2-phase double-buffered LDS:
// stage tile k+1 via async global_load_lds during compute of tile k, one
// barrier per k-step.
// MODE 0: fp32 row-major out (O-proj).
// MODE 1: bf16; z=0/1 (Q/K) -> [B,H,S,DK]; z=2 (V) -> [B,H,DK,S]. Both
//         epilogues repack through per-wave LDS (aliasing As, post-barrier)
//         so all global stores are 16B coalesced; each lane handles TWO
//         short8 per strip row (full 16x64 coverage).
// ---------------------------------------------------------------------------
template <int MODE>
__global__ __launch_bounds__(256) void gemm_bf16_kernel(
    const unsigned short* __restrict__ Ah, const unsigned short* __restrict__ Wh,
    const float* __restrict__ bq, const float* __restrict__ bk,
    const float* __restrict__ bv, void* __restrict__ outv)
{
    __shared__ __align__(16) unsigned short As[2][128 * 32];   // [buf][m][k]
    __shared__ __align__(16) unsigned short Bs[2][128 * 32];   // [buf][n][k]

    const int tid  = threadIdx.x;
    const int wave = tid >> 6;
    const int lane = tid & 63;
    const int quad = lane >> 4;
    const int l15  = lane & 15;
    const int z    = (MODE == 1) ? blockIdx.z : 0;
    const int m0   = blockIdx.x * 128;
    const int n0   = blockIdx.y * 128;
    const int wrow = (wave >> 1) * 64;
    const int wcol = (wave & 1) * 64;

    const unsigned short* A = Ah + (size_t)z * M_ * D_;
    const unsigned short* W = Wh + (size_t)z * D_ * D_;

    const int srow   = tid >> 2;          // 0..63
    const int schunk = (tid & 3) * 8;

#define STAGE_G(BUF, K0)                                                     \
    {                                                                        \
        GLOAD_LDS16(A + (size_t)(m0 + srow) * D_ + (K0) + schunk,            \
                    &As[BUF][wave * 512]);                                   \
        GLOAD_LDS16(W + (size_t)(n0 + srow) * D_ + (K0) + schunk,            \
                    &Bs[BUF][wave * 512]);                                   \
        GLOAD_LDS16(A + (size_t)(m0 + 64 + srow) * D_ + (K0) + schunk,       \
                    &As[BUF][2048 + wave * 512]);                            \
        GLOAD_LDS16(W + (size_t)(n0 + 64 + srow) * D_ + (K0) + schunk,       \
                    &Bs[BUF][2048 + wave * 512]);                            \
    }

    floatx4 acc[4][4] = {};

    STAGE_G(0, 0);
    __syncthreads();

    for (int k0 = 0; k0 < D_; k0 += 32) {
        const int cur = (k0 >> 5) & 1;
        if (k0 + 32 < D_) STAGE_G(cur ^ 1, k0 + 32);

        short8 af[4], bf[4];
#pragma unroll
        for (int i = 0; i < 4; ++i)
            af[i] = *(const short8*)&As[cur][(wrow + i * 16 + l15) * 32 + quad * 8];
#pragma unroll
        for (int j = 0; j < 4; ++j)
            bf[j] = *(const short8*)&Bs[cur][(wcol + j * 16 + l15) * 32 + quad * 8];
#pragma unroll
        for (int i = 0; i < 4; ++i)
#pragma unroll
            for (int j = 0; j < 4; ++j)
                acc[i][j] = __builtin_amdgcn_mfma_f32_16x16x32_bf16(
                    af[i], bf[j], acc[i][j], 0, 0, 0);

        __syncthreads();   // drains staged DMA (after full MFMA cover) + LDS
    }
#undef STAGE_G

    const float* bias = (MODE == 0) ? bq : (z == 0) ? bq : (z == 1) ? bk : bv;

    if (MODE == 1) {
        // LDS repack epilogues; As free after final barrier. 16x68 strip/wave.
        unsigned short* Tw = (unsigned short*)As + wave * 16 * 68;
        const int bg = m0 >> 11;

        if (z == 2) {
            // V^T: [B,H,DK,S]; strip rows = n (dk), cols = m (s)
            const int s0g = (m0 & (S_ - 1)) + wrow + quad * 16;
#pragma unroll
            for (int j = 0; j < 4; ++j) {
                const int n = n0 + wcol + j * 16 + l15;
                const float bn = bias[n];
#pragma unroll
                for (int i = 0; i < 4; ++i)
#pragma unroll
                    for (int reg = 0; reg < 4; ++reg)
                        Tw[l15 * 68 + i * 16 + quad * 4 + reg] =
                            f2bf(acc[i][j][reg] + bn);
                // wave-local LDS: same-wave DS ops are in-order
                short8 r0 = *(const short8*)&Tw[l15 * 68 + quad * 16];
                short8 r1 = *(const short8*)&Tw[l15 * 68 + quad * 16 + 8];
                const int h = n >> 6, d = n & 63;
                unsigned short* dp = (unsigned short*)outv + 2 * (size_t)M_ * D_ +
                    (((size_t)(bg * H_ + h)) * DK_ + d) * S_ + s0g;
                *(short8*)(dp) = r0;
                *(short8*)(dp + 8) = r1;
            }
        } else {
            // Q/K: [B,H,S,DK]; strip rows = m (s), cols = n (dk). Wave's
            // n-range [n0+wcol, +64) is exactly one head -> rows contiguous.
            const int hq = (n0 + wcol) >> 6;
            const int sb = (m0 & (S_ - 1)) + wrow;
            unsigned short* dstz = (unsigned short*)outv + (size_t)z * M_ * D_;
#pragma unroll
            for (int i = 0; i < 4; ++i) {
#pragma unroll
                for (int j = 0; j < 4; ++j) {
                    const float bn = bias[n0 + wcol + j * 16 + l15];
#pragma unroll
                    for (int reg = 0; reg < 4; ++reg)
                        Tw[(quad * 4 + reg) * 68 + j * 16 + l15] =
                            f2bf(acc[i][j][reg] + bn);
                }
                short8 r0 = *(const short8*)&Tw[l15 * 68 + quad * 16];
                short8 r1 = *(const short8*)&Tw[l15 * 68 + quad * 16 + 8];
                unsigned short* dp = dstz +
                    (((size_t)bg * H_ + hq) * S_ + sb + i * 16 + l15) * DK_ +
                    quad * 16;
                *(short8*)dp = r0;
                *(short8*)(dp + 8) = r1;
            }
        }
        return;
    }

    // MODE 0: fp32 row-major (64B-contiguous per store instr)
#pragma unroll
    for (int j = 0; j < 4; ++j) {
        const int n = n0 + wcol + j * 16 + l15;
        const float bn = bias[n];
#pragma unroll
        for (int i = 0; i < 4; ++i) {
#pragma unroll
            for (int reg = 0; reg < 4; ++reg) {
                const int m = m0 + wrow + i * 16 + quad * 4 + reg;
                ((float*)outv)[(size_t)m * D_ + n] = acc[i][j][reg] + bn;
            }
        }
    }
}

// ---------------------------------------------------------------------------
// RoPE tables: tab[s][j] = (cos, sin)(s * 10000^(-2j/64)), s<2048, j<32.
// 65536 threads, one sinf/cosf each (~2 us). Written into the Ah region,
// which is dead after gemm_bf16<1> (stream-ordered).
// ---------------------------------------------------------------------------
__global__ __launch_bounds__(256) void rope_tab_kernel(float* __restrict__ tab)
{
    const int idx = blockIdx.x * 256 + threadIdx.x;   // 0..65535
    const int s = idx >> 5, j = idx & 31;
    // inv_freq = 10000^(-2j/64) = exp2(-(2j/64)*log2(10000))
    const float inv_freq = exp2f((float)(2 * j) * (-13.28771237954945f / 64.f));
    const float ang = (float)s * inv_freq;
    tab[idx * 2]     = cosf(ang);
    tab[idx * 2 + 1] = sinf(ang);
}

// ---------------------------------------------------------------------------
// RoPE in-place on bf16 Q and K ([B*H, S, DK] compact). One wave per row.
// Table-driven: 8B cached read + 2 FMA per element (was powf+sinf+cosf,
// ~150 VALU inst/element -> VALU-bound; Appendix-B RoPE trap).
// ---------------------------------------------------------------------------
__global__ __launch_bounds__(256) void rope_kernel(unsigned short* __restrict__ Q,
                                                   unsigned short* __restrict__ K,
                                                   const float* __restrict__ tab)
{
    const int wave = blockIdx.x * 4 + (threadIdx.x >> 6);
    const int lane = threadIdx.x & 63;
    const int rowsPer = B_ * H_ * S_;

    unsigned short* base = (wave < rowsPer) ? Q : K;
    const int row = (wave < rowsPer) ? wave : wave - rowsPer;
    const int s = row & (S_ - 1);

    unsigned short* p = base + (size_t)row * DK_;
    const float v = bf2f(p[lane]);

    const int j = lane & 31;
    const float2 cs = ((const float2*)tab)[s * 32 + j];

    const int partner = (lane < 32) ? (2 * lane + 1) : (2 * (lane - 32));
    const float sign = (lane < 32) ? -1.0f : 1.0f;
    const float pv = __shfl(v, partner);

    p[lane] = f2bf(v * cs.x + sign * pv * cs.y);
}

// ---------------------------------------------------------------------------
// MFMA flash attention, LDS-staged K/V via async global_load_lds (T3 2-phase).
// Grid 2048: one 64-row q-tile per block. L: xcd=L&7, bh=((L>>3)&7)*8+xcd,
// qt=31-(L>>6) (longest-first). All q-blocks of a head share an XCD.
// Defer-max (T13, THR=8 exp2-domain). P strip now XOR-swizzled (same scheme
// as Ks/Vs) instead of +8-padded: LDS = 16+16+8 = 40 KB exactly -> 4
// blocks/CU (was 41 KB -> 3). launch_bounds(256,4): VGPR cap 128 >= 68.
// ---------------------------------------------------------------------------
__global__ __launch_bounds__(256, 4) void attn_kernel(
    const unsigned short* __restrict__ Qh, const unsigned short* __restrict__ Kh,
    const unsigned short* __restrict__ Vt, unsigned short* __restrict__ ctx)
{
    __shared__ __align__(16) unsigned short Ks[2][64 * 64];   // [s][dk] swz
    __shared__ __align__(16) unsigned short Vs[2][64 * 64];   // [dk][s] swz
    __shared__ __align__(16) short Pw[4][16 * 64];            // per-wave P, swz

    const int tid  = threadIdx.x;
    const int wave = tid >> 6;
    const int lane = tid & 63;
    const int quad = lane >> 4;
    const int l15  = lane & 15;

    const int L  = blockIdx.x;
    const int bh = ((L >> 3) & 7) * 8 + (L & 7);
    const int qt = 31 - (L >> 6);        // longest-first dispatch
    const int q0 = qt * 64;

    const float c2 = 0.18033688011f;   // 0.125 * log2(e)

    const unsigned short* Kbase = Kh + (size_t)bh * S_ * DK_;
    const unsigned short* Vbase = Vt + (size_t)bh * DK_ * S_;
    const int b = bh >> 4, h = bh & 15;

    short* Pme = &Pw[wave][0];

    const unsigned short* Qrow =
        Qh + ((size_t)bh * S_ + q0 + wave * 16 + l15) * DK_;
    short8 aQ[2];
    aQ[0] = *(const short8*)(Qrow + quad * 8);
    aQ[1] = *(const short8*)(Qrow + 32 + quad * 8);

    // staging lane map: wave stages 8 rows x 8 granules (16B) per round;
    // source granule pre-swizzled so LDS (row, g) holds global (row, g^(row&7))
    const int srow = lane >> 3;              // 0..7: row within wave's strip
    const int sg   = (lane & 7) ^ srow;      // swizzled source granule
    const unsigned short* kSrc = Kbase + (size_t)(wave * 8 + srow) * DK_ + sg * 8;
    const unsigned short* vSrc = Vbase + (size_t)(wave * 8 + srow) * S_ + sg * 8;

    floatx4 acc[4] = {};
    float m_i[4] = {-INFINITY, -INFINITY, -INFINITY, -INFINITY};
    float l_i[4] = {0.f, 0.f, 0.f, 0.f};

    // prologue: stage tile j0=0 into buffer 0 (K rows: +rd*32 rows; V: same)
#pragma unroll
    for (int rd = 0; rd < 2; ++rd) {
        GLOAD_LDS16(kSrc + (size_t)rd * 32 * DK_, &Ks[0][rd * 2048 + wave * 512]);
        GLOAD_LDS16(vSrc + (size_t)rd * 32 * S_,  &Vs[0][rd * 2048 + wave * 512]);
    }
    __syncthreads();

    int buf = 0;
    for (int j0 = 0; j0 <= q0; j0 += 64) {
        // async stage of NEXT tile into the other buffer (overlaps compute)
        if (j0 + 64 <= q0) {
#pragma unroll
            for (int rd = 0; rd < 2; ++rd) {
                GLOAD_LDS16(kSrc + (size_t)(j0 + 64 + rd * 32) * DK_,
                            &Ks[buf ^ 1][rd * 2048 + wave * 512]);
                GLOAD_LDS16(vSrc + (j0 + 64) + (size_t)rd * 32 * S_,
                            &Vs[buf ^ 1][rd * 2048 + wave * 512]);
            }
        }

        // QK^T from LDS K tile (swizzled ds_read_b128)
        floatx4 st[4] = {};
#pragma unroll
        for (int t = 0; t < 4; ++t)
#pragma unroll
            for (int kh = 0; kh < 2; ++kh) {
                short8 kf = *(const short8*)&Ks[buf][(t * 16 + l15) * 64 +
                              ((((kh << 2) + quad) ^ (l15 & 7)) << 3)];
                st[t] = __builtin_amdgcn_mfma_f32_16x16x32_bf16(
                    aQ[kh], kf, st[t], 0, 0, 0);
            }

        // causal mask (diag tile only; wave-uniform branch)
        if (j0 == q0) {
#pragma unroll
            for (int t = 0; t < 4; ++t)
#pragma unroll
                for (int reg = 0; reg < 4; ++reg)
                    if (t * 16 + l15 > wave * 16 + quad * 4 + reg)
                        st[t][reg] = -INFINITY;
        }

        // online softmax, exp2 domain; defer-max; packed bf16 P-store.
        // P layout swizzled: (row r, col c) at r*64 + ((c>>3 ^ (r&7))<<3)+(c&7)
#pragma unroll
        for (int reg = 0; reg < 4; ++reg) {
            float rmx = fmaxf(fmaxf(st[0][reg], st[1][reg]),
                              fmaxf(st[2][reg], st[3][reg]));
            rmx = rowmax16(rmx);
            const float pm = rmx * c2;
            if (__ballot(pm > m_i[reg] + 8.0f) != 0ull) {
                const float m2 = fmaxf(m_i[reg], pm);
                const float alpha = exp2f(m_i[reg] - m2);
                l_i[reg] *= alpha;
                m_i[reg] = m2;
                if (__ballot(alpha == 1.0f) != ~0ull) {
#pragma unroll
                    for (int t = 0; t < 4; ++t) acc[t][reg] *= alpha;
                }
            }
            const float m2v = m_i[reg];

            const float p0 = exp2f(fmaf(st[0][reg], c2, -m2v));
            const float p1 = exp2f(fmaf(st[1][reg], c2, -m2v));
            const float p2 = exp2f(fmaf(st[2][reg], c2, -m2v));
            const float p3 = exp2f(fmaf(st[3][reg], c2, -m2v));

            const unsigned pk01 = cvt_pk_bf16(p0, p1);
            const unsigned pk23 = cvt_pk_bf16(p2, p3);
            const int r   = quad * 4 + reg;
            const int sw  = r & 7;
            const int ghi = l15 >> 3;        // col granule high bit
            short* prow = Pme + r * 64 + (l15 & 7);
            prow[((0 + ghi) ^ sw) << 3] = (short)(unsigned short)pk01;
            prow[((2 + ghi) ^ sw) << 3] = (short)(unsigned short)(pk01 >> 16);
            prow[((4 + ghi) ^ sw) << 3] = (short)(unsigned short)pk23;
            prow[((6 + ghi) ^ sw) << 3] = (short)(unsigned short)(pk23 >> 16);

            float rs = (p0 + p1) + (p2 + p3);
            rs = rowsum16(rs);
            l_i[reg] += rs;
        }

        // PV: P A-frags from per-wave LDS (swizzled), V B-frags from LDS tile
#pragma unroll
        for (int kh = 0; kh < 2; ++kh) {
            short8 aP = *(const short8*)&Pme[l15 * 64 +
                          ((((kh << 2) + quad) ^ (l15 & 7)) << 3)];
#pragma unroll
            for (int t = 0; t < 4; ++t) {
                short8 vf = *(const short8*)&Vs[buf][(t * 16 + l15) * 64 +
                              ((((kh << 2) + quad) ^ (l15 & 7)) << 3)];
                acc[t] = __builtin_amdgcn_mfma_f32_16x16x32_bf16(
                    aP, vf, acc[t], 0, 0, 0);
            }
        }

        // flip buffers; __syncthreads drains vmcnt (staged DMA) + lgkmcnt
        __syncthreads();
        buf ^= 1;
    }

    // epilogue
#pragma unroll
    for (int reg = 0; reg < 4; ++reg) {
        const float inv = 1.0f / l_i[reg];
        const int q = q0 + wave * 16 + quad * 4 + reg;
        unsigned short* orow = ctx + ((size_t)b * S_ + q) * D_ + h * DK_;
#pragma unroll
        for (int t = 0; t < 4; ++t)
            orow[t * 16 + l15] = f2bf(acc[t][reg] * inv);
    }
}

// ---------------------------------------------------------------------------
extern "C" void kernel_launch(void* const* d_in, const int* in_sizes, int n_in,
                              void* d_out, int out_size, void* d_ws, size_t ws_size,
                              hipStream_t stream)
{
    const float* query = (const float*)d_in[0];
    const float* key   = (const float*)d_in[1];
    const float* value = (const float*)d_in[2];
    const float* w_q = (const float*)d_in[4];
    const float* b_q = (const float*)d_in[5];
    const float* w_k = (const float*)d_in[6];
    const float* b_k = (const float*)d_in[7];
    const float* w_v = (const float*)d_in[8];
    const float* b_v = (const float*)d_in[9];
    const float* w_o = (const float*)d_in[10];
    const float* b_o = (const float*)d_in[11];
    float* out = (float*)d_out;

    char* ws = (char*)d_ws;
    const size_t half = (size_t)M_ * D_ * sizeof(unsigned short);   // 16.78 MB
    unsigned short* Ah   = (unsigned short*)(ws);                    // [3][M,D] bf16
    unsigned short* Wh   = (unsigned short*)(ws + 3 * half);         // [3][D,D]
    unsigned short* Woh  = (unsigned short*)(ws + 3 * half + 3 * half / 8);
    unsigned short* QKVb = (unsigned short*)(ws + 3 * half + 4 * half / 8);
    unsigned short* Ctxh = (unsigned short*)(ws + 6 * half + 4 * half / 8);
    float*          Rtab = (float*)ws;   // aliases Ah: dead after gemm<1>

    cvt_inputs_kernel<<<dim3(M_ * D_ / 1024, 1, 3), 256, 0, stream>>>(
        query, key, value, Ah);
    cvt_weights_kernel<<<dim3(D_ * D_ / 1024, 1, 4), 256, 0, stream>>>(
        w_q, w_k, w_v, w_o, Wh, Woh);

    gemm_bf16_kernel<1><<<dim3(M_ / 128, D_ / 128, 3), 256, 0, stream>>>(
        Ah, Wh, b_q, b_k, b_v, QKVb);

    unsigned short* Qb = QKVb;
    unsigned short* Kb = QKVb + (size_t)M_ * D_;
    unsigned short* Vb = QKVb + 2 * (size_t)M_ * D_;   // transposed [B,H,DK,S]

    rope_tab_kernel<<<(S_ * 32) / 256, 256, 0, stream>>>(Rtab);
    rope_kernel<<<(2 * B_ * H_ * S_) / 4, 256, 0, stream>>>(Qb, Kb, Rtab);

    attn_kernel<<<dim3(2048), 256, 0, stream>>>(Qb, Kb, Vb, Ctxh);

    gemm_bf16_kernel<0><<<dim3(M_ / 128, D_ / 128, 1), 256, 0, stream>>>(
        Ctxh, Woh, b_o, b_o, b_o, out);
}

// Round 8
// 373.067 us; speedup vs baseline: 1.1985x; 1.0555x over previous
//
#include <hip/hip_runtime.h>
#include <hip/hip_bf16.h>
#include <math.h>

#define B_  4
#define S_  2048
#define D_  1024
#define H_  16
#define DK_ 64
#define M_  (B_ * S_)   // 8192 rows

typedef short short8 __attribute__((ext_vector_type(8)));
typedef float floatx4 __attribute__((ext_vector_type(4)));

__device__ inline unsigned short f2bf(float x) {
    unsigned u = __float_as_uint(x);
    u = (u + 0x7fff + ((u >> 16) & 1)) >> 16;   // round-to-nearest-even
    return (unsigned short)u;
}
__device__ inline float bf2f(unsigned short h) {
    return __uint_as_float(((unsigned)h) << 16);
}

// packed f32x2 -> bf16x2 (RNE), single VALU op
__device__ inline unsigned cvt_pk_bf16(float lo, float hi) {
    unsigned r;
    asm("v_cvt_pk_bf16_f32 %0, %1, %2" : "=v"(r) : "v"(lo), "v"(hi));
    return r;
}

// DPP row rotate (within 16-lane row) — VALU-pipe cross-lane
template <int K>
__device__ inline float dpp_ror(float x) {
    return __uint_as_float((unsigned)__builtin_amdgcn_update_dpp(
        0, (int)__float_as_uint(x), 0x120 | K, 0xF, 0xF, true));
}
__device__ inline float rowmax16(float x) {
    x = fmaxf(x, dpp_ror<8>(x));
    x = fmaxf(x, dpp_ror<4>(x));
    x = fmaxf(x, dpp_ror<2>(x));
    x = fmaxf(x, dpp_ror<1>(x));
    return x;
}
__device__ inline float rowsum16(float x) {
    x += dpp_ror<8>(x);
    x += dpp_ror<4>(x);
    x += dpp_ror<2>(x);
    x += dpp_ror<1>(x);
    return x;
}

#define GLOAD_LDS16(g, l)                                          \
    __builtin_amdgcn_global_load_lds(                              \
        (const __attribute__((address_space(1))) void*)(g),        \
        (__attribute__((address_space(3))) void*)(l), 16, 0, 0)

// ---------------------------------------------------------------------------
// fp32 -> bf16 converters
// ---------------------------------------------------------------------------
__global__ __launch_bounds__(256) void cvt_inputs_kernel(
    const float* __restrict__ q, const float* __restrict__ k,
    const float* __restrict__ v, unsigned short* __restrict__ Ah)
{
    const int z = blockIdx.z;
    const float* src = (z == 0) ? q : (z == 1) ? k : v;
    unsigned short* dst = Ah + (size_t)z * M_ * D_;
    const size_t i = ((size_t)blockIdx.x * 256 + threadIdx.x) * 4;
    float4 f = *(const float4*)(src + i);
    ushort4 o;
    o.x = f2bf(f.x); o.y = f2bf(f.y); o.z = f2bf(f.z); o.w = f2bf(f.w);
    *(ushort4*)(dst + i) = o;
}

// z<4: weight conversion. z==4 (first 256 blocks): RoPE cos/sin table
// tab[s][j] = (cos,sin)(s * 10000^(-2j/64)), s<2048, j<32.
__global__ __launch_bounds__(256) void cvt_weights_kernel(
    const float* __restrict__ wq, const float* __restrict__ wk,
    const float* __restrict__ wv, const float* __restrict__ wo,
    unsigned short* __restrict__ Wh, unsigned short* __restrict__ Woh,
    float* __restrict__ tab)
{
    const int z = blockIdx.z;
    if (z == 4) {
        if (blockIdx.x >= 256) return;
        const int idx = blockIdx.x * 256 + threadIdx.x;   // 0..65535
        const int s = idx >> 5, j = idx & 31;
        const float inv_freq =
            exp2f((float)(2 * j) * (-13.28771237954945f / 64.f));
        const float ang = (float)s * inv_freq;
        tab[idx * 2]     = cosf(ang);
        tab[idx * 2 + 1] = sinf(ang);
        return;
    }
    const float* src = (z == 0) ? wq : (z == 1) ? wk : (z == 2) ? wv : wo;
    unsigned short* dst = (z < 3) ? (Wh + (size_t)z * D_ * D_) : Woh;
    const size_t i = ((size_t)blockIdx.x * 256 + threadIdx.x) * 4;
    float4 f = *(const float4*)(src + i);
    ushort4 o;
    o.x = f2bf(f.x); o.y = f2bf(f.y); o.z = f2bf(f.z); o.w = f2bf(f.w);
    *(ushort4*)(dst + i) = o;
}

// ---------------------------------------------------------------------------
// bf16 MFMA NT-GEMM: C = A @ W^T + bias.  2-phase double-buffered LDS.
// MODE 0: fp32 row-major out (O-proj).
// MODE 1: bf16; z=0/1 (Q/K) -> [B,H,S,DK] with FUSED RoPE on epilogue
//         read-back (rot = cat(-x[1::2], x[::2]); partner bf16s are the
//         low/high halves of the partner half-row's dwords); z=2 (V) ->
//         [B,H,DK,S]. All global stores 16B coalesced.
// ---------------------------------------------------------------------------
template <int MODE>
__global__ __launch_bounds__(256) void gemm_bf16_kernel(
    const unsigned short* __restrict__ Ah, const unsigned short* __restrict__ Wh,
    const float* __restrict__ bq, const float* __restrict__ bk,
    const float* __restrict__ bv, void* __restrict__ outv,
    const float* __restrict__ tab)
{
    __shared__ __align__(16) unsigned short As[2][128 * 32];   // [buf][m][k]
    __shared__ __align__(16) unsigned short Bs[2][128 * 32];   // [buf][n][k]

    const int tid  = threadIdx.x;
    const int wave = tid >> 6;
    const int lane = tid & 63;
    const int quad = lane >> 4;
    const int l15  = lane & 15;
    const int z    = (MODE == 1) ? blockIdx.z : 0;
    const int m0   = blockIdx.x * 128;
    const int n0   = blockIdx.y * 128;
    const int wrow = (wave >> 1) * 64;
    const int wcol = (wave & 1) * 64;

    const unsigned short* A = Ah + (size_t)z * M_ * D_;
    const unsigned short* W = Wh + (size_t)z * D_ * D_;

    const int srow   = tid >> 2;          // 0..63
    const int schunk = (tid & 3) * 8;

#define STAGE_G(BUF, K0)                                                     \
    {                                                                        \
        GLOAD_LDS16(A + (size_t)(m0 + srow) * D_ + (K0) + schunk,            \
                    &As[BUF][wave * 512]);                                   \
        GLOAD_LDS16(W + (size_t)(n0 + srow) * D_ + (K0) + schunk,            \
                    &Bs[BUF][wave * 512]);                                   \
        GLOAD_LDS16(A + (size_t)(m0 + 64 + srow) * D_ + (K0) + schunk,       \
                    &As[BUF][2048 + wave * 512]);                            \
        GLOAD_LDS16(W + (size_t)(n0 + 64 + srow) * D_ + (K0) + schunk,       \
                    &Bs[BUF][2048 + wave * 512]);                            \
    }

    floatx4 acc[4][4] = {};

    STAGE_G(0, 0);
    __syncthreads();

    for (int k0 = 0; k0 < D_; k0 += 32) {
        const int cur = (k0 >> 5) & 1;
        if (k0 + 32 < D_) STAGE_G(cur ^ 1, k0 + 32);

        short8 af[4], bf[4];
#pragma unroll
        for (int i = 0; i < 4; ++i)
            af[i] = *(const short8*)&As[cur][(wrow + i * 16 + l15) * 32 + quad * 8];
#pragma unroll
        for (int j = 0; j < 4; ++j)
            bf[j] = *(const short8*)&Bs[cur][(wcol + j * 16 + l15) * 32 + quad * 8];
#pragma unroll
        for (int i = 0; i < 4; ++i)
#pragma unroll
            for (int j = 0; j < 4; ++j)
                acc[i][j] = __builtin_amdgcn_mfma_f32_16x16x32_bf16(
                    af[i], bf[j], acc[i][j], 0, 0, 0);

        __syncthreads();   // drains staged DMA (after full MFMA cover) + LDS
    }
#undef STAGE_G

    const float* bias = (MODE == 0) ? bq : (z == 0) ? bq : (z == 1) ? bk : bv;

    if (MODE == 1) {
        // LDS repack epilogues; As free after final barrier. 16x68 strip/wave.
        unsigned short* Tw = (unsigned short*)As + wave * 16 * 68;
        const int bg = m0 >> 11;

        if (z == 2) {
            // V^T: [B,H,DK,S]; strip rows = n (dk), cols = m (s)
            const int s0g = (m0 & (S_ - 1)) + wrow + quad * 16;
#pragma unroll
            for (int j = 0; j < 4; ++j) {
                const int n = n0 + wcol + j * 16 + l15;
                const float bn = bias[n];
#pragma unroll
                for (int i = 0; i < 4; ++i)
#pragma unroll
                    for (int reg = 0; reg < 4; ++reg)
                        Tw[l15 * 68 + i * 16 + quad * 4 + reg] =
                            f2bf(acc[i][j][reg] + bn);
                // wave-local LDS: same-wave DS ops are in-order
                short8 r0 = *(const short8*)&Tw[l15 * 68 + quad * 16];
                short8 r1 = *(const short8*)&Tw[l15 * 68 + quad * 16 + 8];
                const int h = n >> 6, d = n & 63;
                unsigned short* dp = (unsigned short*)outv + 2 * (size_t)M_ * D_ +
                    (((size_t)(bg * H_ + h)) * DK_ + d) * S_ + s0g;
                *(short8*)(dp) = r0;
                *(short8*)(dp + 8) = r1;
            }
        } else {
            // Q/K with fused RoPE. Strip rows = m (s), cols = n (dk = 0..63,
            // one full head per wave). Lane handles row l15, d in
            // [16*quad, 16*quad+16). Partner half-row = bytes
            // [(quad&1)*64, +64): for quad<2 partners are ODD elements
            // (high dword halves, sign -); for quad>=2 EVEN (low, sign +).
            const int hq = (n0 + wcol) >> 6;
            const int sb = (m0 & (S_ - 1)) + wrow;
            unsigned short* dstz = (unsigned short*)outv + (size_t)z * M_ * D_;
            const float sgn = (quad < 2) ? -1.f : 1.f;
#pragma unroll
            for (int i = 0; i < 4; ++i) {
#pragma unroll
                for (int j = 0; j < 4; ++j) {
                    const float bn = bias[n0 + wcol + j * 16 + l15];
#pragma unroll
                    for (int reg = 0; reg < 4; ++reg)
                        Tw[(quad * 4 + reg) * 68 + j * 16 + l15] =
                            f2bf(acc[i][j][reg] + bn);
                }
                const unsigned short* Trow = Tw + l15 * 68;
                uint4 xa = *(const uint4*)(Trow + quad * 16);
                uint4 xb = *(const uint4*)(Trow + quad * 16 + 8);
                const unsigned short* Prow = Trow + (quad & 1) * 32;
                uint4 pa = *(const uint4*)(Prow);
                uint4 pb = *(const uint4*)(Prow + 8);
                uint4 pc = *(const uint4*)(Prow + 16);
                uint4 pd = *(const uint4*)(Prow + 24);
                const int s = sb + i * 16 + l15;
                // tab = float2[2048][32]; j-range = (quad&1)*16 + [0,16)
                const float4* tb =
                    (const float4*)tab + (s * 16 + (quad & 1) * 8);
                const unsigned xw[8] = {xa.x, xa.y, xa.z, xa.w,
                                        xb.x, xb.y, xb.z, xb.w};
                const unsigned pw[16] = {pa.x, pa.y, pa.z, pa.w,
                                         pb.x, pb.y, pb.z, pb.w,
                                         pc.x, pc.y, pc.z, pc.w,
                                         pd.x, pd.y, pd.z, pd.w};
                unsigned ow[8];
#pragma unroll
                for (int c2 = 0; c2 < 8; ++c2) {
                    const float4 cs = tb[c2];
                    const float xe = __uint_as_float(xw[c2] << 16);
                    const float xo = __uint_as_float(xw[c2] & 0xffff0000u);
                    const unsigned pe = pw[2 * c2], po = pw[2 * c2 + 1];
                    const float pre = (quad < 2)
                        ? __uint_as_float(pe & 0xffff0000u)
                        : __uint_as_float(pe << 16);
                    const float pro = (quad < 2)
                        ? __uint_as_float(po & 0xffff0000u)
                        : __uint_as_float(po << 16);
                    const float o0 = fmaf(pre, sgn * cs.y, xe * cs.x);
                    const float o1 = fmaf(pro, sgn * cs.w, xo * cs.z);
                    ow[c2] = cvt_pk_bf16(o0, o1);
                }
                unsigned short* dp = dstz +
                    (((size_t)bg * H_ + hq) * S_ + sb + i * 16 + l15) * DK_ +
                    quad * 16;
                uint4 olo; olo.x = ow[0]; olo.y = ow[1];
                           olo.z = ow[2]; olo.w = ow[3];
                uint4 ohi; ohi.x = ow[4]; ohi.y = ow[5];
                           ohi.z = ow[6]; ohi.w = ow[7];
                *(uint4*)dp = olo;
                *(uint4*)(dp + 8) = ohi;
            }
        }
        return;
    }

    // MODE 0: fp32 row-major (64B-contiguous per store instr)
#pragma unroll
    for (int j = 0; j < 4; ++j) {
        const int n = n0 + wcol + j * 16 + l15;
        const float bn = bias[n];
#pragma unroll
        for (int i = 0; i < 4; ++i) {
#pragma unroll
            for (int reg = 0; reg < 4; ++reg) {
                const int m = m0 + wrow + i * 16 + quad * 4 + reg;
                ((float*)outv)[(size_t)m * D_ + n] = acc[i][j][reg] + bn;
            }
        }
    }
}

// ---------------------------------------------------------------------------
// MFMA flash attention, LDS-staged K/V via async global_load_lds (T3 2-phase).
// Grid 2048: one 64-row q-tile per block. L: xcd=L&7, bh=((L>>3)&7)*8+xcd,
// qt=31-(L>>6) (longest-first). All q-blocks of a head share an XCD.
// Defer-max (T13, THR=8 exp2-domain). P strip XOR-swizzled; LDS 40KB ->
// 4 blocks/CU. T5 setprio(1) around MFMA clusters (blocks phase-independent).
// ---------------------------------------------------------------------------
__global__ __launch_bounds__(256, 4) void attn_kernel(
    const unsigned short* __restrict__ Qh, const unsigned short* __restrict__ Kh,
    const unsigned short* __restrict__ Vt, unsigned short* __restrict__ ctx)
{
    __shared__ __align__(16) unsigned short Ks[2][64 * 64];   // [s][dk] swz
    __shared__ __align__(16) unsigned short Vs[2][64 * 64];   // [dk][s] swz
    __shared__ __align__(16) short Pw[4][16 * 64];            // per-wave P, swz

    const int tid  = threadIdx.x;
    const int wave = tid >> 6;
    const int lane = tid & 63;
    const int quad = lane >> 4;
    const int l15  = lane & 15;

    const int L  = blockIdx.x;
    const int bh = ((L >> 3) & 7) * 8 + (L & 7);
    const int qt = 31 - (L >> 6);        // longest-first dispatch
    const int q0 = qt * 64;

    const float c2 = 0.18033688011f;   // 0.125 * log2(e)

    const unsigned short* Kbase = Kh + (size_t)bh * S_ * DK_;
    const unsigned short* Vbase = Vt + (size_t)bh * DK_ * S_;
    const int b = bh >> 4, h = bh & 15;

    short* Pme = &Pw[wave][0];

    const unsigned short* Qrow =
        Qh + ((size_t)bh * S_ + q0 + wave * 16 + l15) * DK_;
    short8 aQ[2];
    aQ[0] = *(const short8*)(Qrow + quad * 8);
    aQ[1] = *(const short8*)(Qrow + 32 + quad * 8);

    // staging lane map: wave stages 8 rows x 8 granules (16B) per round;
    // source granule pre-swizzled so LDS (row, g) holds global (row, g^(row&7))
    const int srow = lane >> 3;              // 0..7: row within wave's strip
    const int sg   = (lane & 7) ^ srow;      // swizzled source granule
    const unsigned short* kSrc = Kbase + (size_t)(wave * 8 + srow) * DK_ + sg * 8;
    const unsigned short* vSrc = Vbase + (size_t)(wave * 8 + srow) * S_ + sg * 8;

    floatx4 acc[4] = {};
    float m_i[4] = {-INFINITY, -INFINITY, -INFINITY, -INFINITY};
    float l_i[4] = {0.f, 0.f, 0.f, 0.f};

    // prologue: stage tile j0=0 into buffer 0 (K rows: +rd*32 rows; V: same)
#pragma unroll
    for (int rd = 0; rd < 2; ++rd) {
        GLOAD_LDS16(kSrc + (size_t)rd * 32 * DK_, &Ks[0][rd * 2048 + wave * 512]);
        GLOAD_LDS16(vSrc + (size_t)rd * 32 * S_,  &Vs[0][rd * 2048 + wave * 512]);
    }
    __syncthreads();

    int buf = 0;
    for (int j0 = 0; j0 <= q0; j0 += 64) {
        // async stage of NEXT tile into the other buffer (overlaps compute)
        if (j0 + 64 <= q0) {
#pragma unroll
            for (int rd = 0; rd < 2; ++rd) {
                GLOAD_LDS16(kSrc + (size_t)(j0 + 64 + rd * 32) * DK_,
                            &Ks[buf ^ 1][rd * 2048 + wave * 512]);
                GLOAD_LDS16(vSrc + (j0 + 64) + (size_t)rd * 32 * S_,
                            &Vs[buf ^ 1][rd * 2048 + wave * 512]);
            }
        }

        // QK^T from LDS K tile (swizzled ds_read_b128)
        floatx4 st[4] = {};
        __builtin_amdgcn_s_setprio(1);
#pragma unroll
        for (int t = 0; t < 4; ++t)
#pragma unroll
            for (int kh = 0; kh < 2; ++kh) {
                short8 kf = *(const short8*)&Ks[buf][(t * 16 + l15) * 64 +
                              ((((kh << 2) + quad) ^ (l15 & 7)) << 3)];
                st[t] = __builtin_amdgcn_mfma_f32_16x16x32_bf16(
                    aQ[kh], kf, st[t], 0, 0, 0);
            }
        __builtin_amdgcn_s_setprio(0);

        // causal mask (diag tile only; wave-uniform branch)
        if (j0 == q0) {
#pragma unroll
            for (int t = 0; t < 4; ++t)
#pragma unroll
                for (int reg = 0; reg < 4; ++reg)
                    if (t * 16 + l15 > wave * 16 + quad * 4 + reg)
                        st[t][reg] = -INFINITY;
        }

        // online softmax, exp2 domain; defer-max; packed bf16 P-store.
        // P layout swizzled: (row r, col c) at r*64 + ((c>>3 ^ (r&7))<<3)+(c&7)
#pragma unroll
        for (int reg = 0; reg < 4; ++reg) {
            float rmx = fmaxf(fmaxf(st[0][reg], st[1][reg]),
                              fmaxf(st[2][reg], st[3][reg]));
            rmx = rowmax16(rmx);
            const float pm = rmx * c2;
            if (__ballot(pm > m_i[reg] + 8.0f) != 0ull) {
                const float m2 = fmaxf(m_i[reg], pm);
                const float alpha = exp2f(m_i[reg] - m2);
                l_i[reg] *= alpha;
                m_i[reg] = m2;
                if (__ballot(alpha == 1.0f) != ~0ull) {
#pragma unroll
                    for (int t = 0; t < 4; ++t) acc[t][reg] *= alpha;
                }
            }
            const float m2v = m_i[reg];

            const float p0 = exp2f(fmaf(st[0][reg], c2, -m2v));
            const float p1 = exp2f(fmaf(st[1][reg], c2, -m2v));
            const float p2 = exp2f(fmaf(st[2][reg], c2, -m2v));
            const float p3 = exp2f(fmaf(st[3][reg], c2, -m2v));

            const unsigned pk01 = cvt_pk_bf16(p0, p1);
            const unsigned pk23 = cvt_pk_bf16(p2, p3);
            const int r   = quad * 4 + reg;
            const int sw  = r & 7;
            const int ghi = l15 >> 3;        // col granule high bit
            short* prow = Pme + r * 64 + (l15 & 7);
            prow[((0 + ghi) ^ sw) << 3] = (short)(unsigned short)pk01;
            prow[((2 + ghi) ^ sw) << 3] = (short)(unsigned short)(pk01 >> 16);
            prow[((4 + ghi) ^ sw) << 3] = (short)(unsigned short)pk23;
            prow[((6 + ghi) ^ sw) << 3] = (short)(unsigned short)(pk23 >> 16);

            float rs = (p0 + p1) + (p2 + p3);
            rs = rowsum16(rs);
            l_i[reg] += rs;
        }

        // PV: P A-frags from per-wave LDS (swizzled), V B-frags from LDS tile
        __builtin_amdgcn_s_setprio(1);
#pragma unroll
        for (int kh = 0; kh < 2; ++kh) {
            short8 aP = *(const short8*)&Pme[l15 * 64 +
                          ((((kh << 2) + quad) ^ (l15 & 7)) << 3)];
#pragma unroll
            for (int t = 0; t < 4; ++t) {
                short8 vf = *(const short8*)&Vs[buf][(t * 16 + l15) * 64 +
                              ((((kh << 2) + quad) ^ (l15 & 7)) << 3)];
                acc[t] = __builtin_amdgcn_mfma_f32_16x16x32_bf16(
                    aP, vf, acc[t], 0, 0, 0);
            }
        }
        __builtin_amdgcn_s_setprio(0);

        // flip buffers; __syncthreads drains vmcnt (staged DMA) + lgkmcnt
        __syncthreads();
        buf ^= 1;
    }

    // epilogue
#pragma unroll
    for (int reg = 0; reg < 4; ++reg) {
        const float inv = 1.0f / l_i[reg];
        const int q = q0 + wave * 16 + quad * 4 + reg;
        unsigned short* orow = ctx + ((size_t)b * S_ + q) * D_ + h * DK_;
#pragma unroll
        for (int t = 0; t < 4; ++t)
            orow[t * 16 + l15] = f2bf(acc[t][reg] * inv);
    }
}

// ---------------------------------------------------------------------------
extern "C" void kernel_launch(void* const* d_in, const int* in_sizes, int n_in,
                              void* d_out, int out_size, void* d_ws, size_t ws_size,
                              hipStream_t stream)
{
    const float* query = (const float*)d_in[0];
    const float* key   = (const float*)d_in[1];
    const float* value = (const float*)d_in[2];
    const float* w_q = (const float*)d_in[4];
    const float* b_q = (const float*)d_in[5];
    const float* w_k = (const float*)d_in[6];
    const float* b_k = (const float*)d_in[7];
    const float* w_v = (const float*)d_in[8];
    const float* b_v = (const float*)d_in[9];
    const float* w_o = (const float*)d_in[10];
    const float* b_o = (const float*)d_in[11];
    float* out = (float*)d_out;

    char* ws = (char*)d_ws;
    const size_t half = (size_t)M_ * D_ * sizeof(unsigned short);   // 16.78 MB
    unsigned short* Ah   = (unsigned short*)(ws);                    // [3][M,D] bf16
    unsigned short* Wh   = (unsigned short*)(ws + 3 * half);         // [3][D,D]
    unsigned short* Woh  = (unsigned short*)(ws + 3 * half + 3 * half / 8);
    unsigned short* QKVb = (unsigned short*)(ws + 3 * half + 4 * half / 8);
    unsigned short* Ctxh = (unsigned short*)(ws + 6 * half + 4 * half / 8);
    float*          Rtab = (float*)Ctxh;   // 512KB table; Ctxh dead until attn

    cvt_inputs_kernel<<<dim3(M_ * D_ / 1024, 1, 3), 256, 0, stream>>>(
        query, key, value, Ah);
    cvt_weights_kernel<<<dim3(D_ * D_ / 1024, 1, 5), 256, 0, stream>>>(
        w_q, w_k, w_v, w_o, Wh, Woh, Rtab);

    gemm_bf16_kernel<1><<<dim3(M_ / 128, D_ / 128, 3), 256, 0, stream>>>(
        Ah, Wh, b_q, b_k, b_v, QKVb, Rtab);

    unsigned short* Qb = QKVb;
    unsigned short* Kb = QKVb + (size_t)M_ * D_;
    unsigned short* Vb = QKVb + 2 * (size_t)M_ * D_;   // transposed [B,H,DK,S]

    attn_kernel<<<dim3(2048), 256, 0, stream>>>(Qb, Kb, Vb, Ctxh);

    gemm_bf16_kernel<0><<<dim3(M_ / 128, D_ / 128, 1), 256, 0, stream>>>(
        Ctxh, Woh, b_o, b_o, b_o, out, Rtab);
}